// Round 6
// baseline (394.076 us; speedup 1.0000x reference)
//
#include <hip/hip_runtime.h>
#include <hip/hip_bf16.h>
#include <math.h>

#define HID 128

typedef __bf16 bf16x8 __attribute__((ext_vector_type(8)));
typedef float f32x4 __attribute__((ext_vector_type(4)));
typedef float nf4 __attribute__((ext_vector_type(4)));   // native vec for nontemporal ops
union BF8 { uint4 u; bf16x8 v; unsigned short s[8]; };

__device__ __forceinline__ unsigned short f2bf(float x) {
  unsigned u = __float_as_uint(x);
  unsigned r = u + 0x7FFFu + ((u >> 16) & 1u);   // RNE (finite inputs)
  return (unsigned short)(r >> 16);
}
__device__ __forceinline__ float bf2f(unsigned short h) {
  return __uint_as_float(((unsigned)h) << 16);
}
__device__ __forceinline__ void ld2bf(const unsigned short* p, float& x, float& y) {
  unsigned v = *(const unsigned*)p;
  x = __uint_as_float((v & 0xFFFFu) << 16);
  y = __uint_as_float(v & 0xFFFF0000u);
}
__device__ __forceinline__ float2 pk_add2(float2 a, float2 b) {
  return make_float2(a.x + b.x, a.y + b.y);
}
__device__ __forceinline__ float2 pk_sub2(float2 a, float2 b) {
  return make_float2(a.x - b.x, a.y - b.y);
}
__device__ __forceinline__ float2 pk_fma2(float2 a, float2 b, float2 c) {
  return make_float2(fmaf(a.x, b.x, c.x), fmaf(a.y, b.y, c.y));
}
__device__ __forceinline__ float2 pk_max2(float2 a, float2 b) {
  return make_float2(fmaxf(a.x, b.x), fmaxf(a.y, b.y));
}
__device__ __forceinline__ float2 pk_muls2(float2 a, float b) {
  return make_float2(a.x * b, a.y * b);
}

// ---------- prep: transposed weights ----------
__global__ void prep3(const float* __restrict__ fc_W, const float* __restrict__ Wl,
                      const float* __restrict__ Wr, const float* __restrict__ We,
                      const float* __restrict__ Wpost, const float* __restrict__ W1,
                      const float* __restrict__ W2, const float* __restrict__ bl,
                      const float* __restrict__ br, const float* __restrict__ gat_bias,
                      const float* __restrict__ bpost,
                      unsigned short* __restrict__ fcTh, unsigned short* __restrict__ fcTl,
                      unsigned short* __restrict__ WnTh, unsigned short* __restrict__ WnTl,
                      unsigned short* __restrict__ WpT, unsigned short* __restrict__ W1T,
                      unsigned short* __restrict__ W2T,
                      float* __restrict__ bxy, float* __restrict__ bpost2) {
  int gid = blockIdx.x * 256 + threadIdx.x;
  if (gid < 32768) {                       // fc_W [128x256] -> fcT hi/lo [256][128]
    int n = gid >> 7, k = gid & 127;
    float x = fc_W[k * 256 + n];
    unsigned short h = f2bf(x);
    fcTh[n * 128 + k] = h;
    fcTl[n * 128 + k] = f2bf(x - bf2f(h));
  } else if (gid < 98304) {                // WnT [512][128] cols=[Wl|Wr|WeA|WeB]
    int i = gid - 32768; int n = i >> 7, k = i & 127;
    float x;
    if (n < 128)      x = Wl[k * 128 + n];
    else if (n < 256) x = Wr[k * 128 + (n - 128)];
    else if (n < 384) x = We[k * 128 + (n - 256)];
    else              x = We[(128 + k) * 128 + (n - 384)];
    unsigned short h = f2bf(x);
    WnTh[n * 128 + k] = h;
    if (n >= 256) WnTl[(n - 256) * 128 + k] = f2bf(x - bf2f(h));
  } else if (gid < 147456) {               // Wpost/W1/W2 -> T [128][128]
    int i = gid - 98304; int which = i >> 14; int j = i & 16383;
    int n = j >> 7, k = j & 127;
    const float* W = (which == 0) ? Wpost : (which == 1) ? W1 : W2;
    unsigned short* T = (which == 0) ? WpT : (which == 1) ? W1T : W2T;
    T[n * 128 + k] = f2bf(W[k * 128 + n]);
  } else if (gid < 147712) {               // bxy = [bl|br]
    int j = gid - 147456;
    bxy[j] = (j < 128) ? bl[j] : br[j - 128];
  } else if (gid < 147840) {               // bpost2 = bpost + gat_bias @ Wpost
    int t = gid - 147712;
    float s = bpost[t];
    for (int k = 0; k < 128; ++k) s += gat_bias[k] * Wpost[k * 128 + t];
    bpost2[t] = s;
  }
}

// ---------- MFMA GEMM (style): C[M x Ncols] = A[M x 128] @ WT^T + bias, split hi/lo ----------
__global__ __launch_bounds__(256) void gemm_mfma(const float* __restrict__ A,
                                                 const unsigned short* __restrict__ WTh,
                                                 const unsigned short* __restrict__ WTl,
                                                 const float* __restrict__ bias,
                                                 float* __restrict__ C, int Ncols) {
  int tid = threadIdx.x;
  int wave = tid >> 6, lane = tid & 63;
  int m = lane & 15, q = lane >> 4;
  int r0 = blockIdx.x * 64 + wave * 16;
  const float* arow = A + (size_t)(r0 + m) * 128 + q * 8;
  BF8 Ah[4], Al[4];
#pragma unroll
  for (int kc = 0; kc < 4; ++kc) {
    float4 x0 = *(const float4*)(arow + kc * 32);
    float4 x1 = *(const float4*)(arow + kc * 32 + 4);
    float xs[8] = {x0.x, x0.y, x0.z, x0.w, x1.x, x1.y, x1.z, x1.w};
#pragma unroll
    for (int j = 0; j < 8; ++j) {
      unsigned short h = f2bf(xs[j]);
      Ah[kc].s[j] = h;
      Al[kc].s[j] = f2bf(xs[j] - bf2f(h));
    }
  }
  int ntiles = Ncols >> 4;
  for (int nt = 0; nt < ntiles; ++nt) {
    const unsigned short* wr  = WTh + (size_t)(nt * 16 + m) * 128 + q * 8;
    const unsigned short* wrl = WTl + (size_t)(nt * 16 + m) * 128 + q * 8;
    f32x4 acc = {0.f, 0.f, 0.f, 0.f};
#pragma unroll
    for (int kc = 0; kc < 4; ++kc) {
      BF8 bh, blo;
      bh.u  = *(const uint4*)(wr + kc * 32);
      blo.u = *(const uint4*)(wrl + kc * 32);
      acc = __builtin_amdgcn_mfma_f32_16x16x32_bf16(Ah[kc].v, bh.v, acc, 0, 0, 0);
      acc = __builtin_amdgcn_mfma_f32_16x16x32_bf16(Al[kc].v, bh.v, acc, 0, 0, 0);
      acc = __builtin_amdgcn_mfma_f32_16x16x32_bf16(Ah[kc].v, blo.v, acc, 0, 0, 0);
    }
    int n = nt * 16 + m;
    float bv = bias ? bias[n] : 0.0f;
#pragma unroll
    for (int i = 0; i < 4; ++i) {
      int row = r0 + q * 4 + i;
      C[(size_t)row * Ncols + n] = acc[i] + bv;
    }
  }
}

// ---------- fused: GroupNorm+modulate (inline A-build) + dual-output node GEMM ----------
__global__ __launch_bounds__(256) void k_nodeP(const float* __restrict__ h_source,
                                               const float* __restrict__ style,
                                               const float* __restrict__ gn_gamma,
                                               const float* __restrict__ gn_beta,
                                               const unsigned short* __restrict__ WnTh,
                                               const unsigned short* __restrict__ WnTl,
                                               const float* __restrict__ bxy,
                                               unsigned short* __restrict__ packed,
                                               unsigned short* __restrict__ xrArr) {
  int tid = threadIdx.x, wave = tid >> 6, lane = tid & 63;
  int m = lane & 15, q = lane >> 4;
  int r0 = blockIdx.x * 128 + wave * 32;
  BF8 Ah[2][4], Al[2][4];
#pragma unroll
  for (int set = 0; set < 2; ++set) {
    int r = r0 + set * 16 + m;
    const float* hrow = h_source + (size_t)r * 128;
    const float* srow = style + (size_t)r * 256;
#pragma unroll
    for (int kc = 0; kc < 4; ++kc) {
      int ch = q * 8 + kc * 32;
      float4 x0 = *(const float4*)(hrow + ch);
      float4 x1 = *(const float4*)(hrow + ch + 4);
      float xs[8] = {x0.x, x0.y, x0.z, x0.w, x1.x, x1.y, x1.z, x1.w};
      float s8 = 0.f, q8 = 0.f;
#pragma unroll
      for (int j = 0; j < 8; ++j) { s8 += xs[j]; q8 += xs[j] * xs[j]; }
      float s16 = s8 + __shfl_xor(s8, 16);
      float q16 = q8 + __shfl_xor(q8, 16);
      float mu = s16 * (1.0f / 16.0f);
      float var = q16 * (1.0f / 16.0f) - mu * mu;
      float rv = rsqrtf(var + 1e-5f);
      float4 g0 = *(const float4*)(gn_gamma + ch);
      float4 g1 = *(const float4*)(gn_gamma + ch + 4);
      float4 be0 = *(const float4*)(gn_beta + ch);
      float4 be1 = *(const float4*)(gn_beta + ch + 4);
      float4 sg0 = *(const float4*)(srow + ch);
      float4 sg1 = *(const float4*)(srow + ch + 4);
      float4 sb0 = *(const float4*)(srow + 128 + ch);
      float4 sb1 = *(const float4*)(srow + 128 + ch + 4);
      float gg[8] = {g0.x, g0.y, g0.z, g0.w, g1.x, g1.y, g1.z, g1.w};
      float bb[8] = {be0.x, be0.y, be0.z, be0.w, be1.x, be1.y, be1.z, be1.w};
      float sg[8] = {sg0.x, sg0.y, sg0.z, sg0.w, sg1.x, sg1.y, sg1.z, sg1.w};
      float sb[8] = {sb0.x, sb0.y, sb0.z, sb0.w, sb1.x, sb1.y, sb1.z, sb1.w};
#pragma unroll
      for (int j = 0; j < 8; ++j) {
        float v = ((xs[j] - mu) * rv * gg[j] + bb[j]) * (1.0f + sg[j]) + sb[j];
        unsigned short h = f2bf(v);
        Ah[set][kc].s[j] = h;
        Al[set][kc].s[j] = f2bf(v - bf2f(h));
      }
    }
  }
  for (int nt = 0; nt < 32; ++nt) {
    f32x4 acc0 = {0.f, 0.f, 0.f, 0.f};
    f32x4 acc1 = {0.f, 0.f, 0.f, 0.f};
    const unsigned short* wr = WnTh + (size_t)(nt * 16 + m) * 128 + q * 8;
    if (nt < 16) {
#pragma unroll
      for (int kc = 0; kc < 4; ++kc) {
        BF8 bh; bh.u = *(const uint4*)(wr + kc * 32);
        acc0 = __builtin_amdgcn_mfma_f32_16x16x32_bf16(Ah[0][kc].v, bh.v, acc0, 0, 0, 0);
        acc1 = __builtin_amdgcn_mfma_f32_16x16x32_bf16(Ah[1][kc].v, bh.v, acc1, 0, 0, 0);
      }
    } else {
      const unsigned short* wl = WnTl + (size_t)((nt - 16) * 16 + m) * 128 + q * 8;
#pragma unroll
      for (int kc = 0; kc < 4; ++kc) {
        BF8 bh, blo;
        bh.u  = *(const uint4*)(wr + kc * 32);
        blo.u = *(const uint4*)(wl + kc * 32);
        acc0 = __builtin_amdgcn_mfma_f32_16x16x32_bf16(Ah[0][kc].v, bh.v, acc0, 0, 0, 0);
        acc0 = __builtin_amdgcn_mfma_f32_16x16x32_bf16(Al[0][kc].v, bh.v, acc0, 0, 0, 0);
        acc0 = __builtin_amdgcn_mfma_f32_16x16x32_bf16(Ah[0][kc].v, blo.v, acc0, 0, 0, 0);
        acc1 = __builtin_amdgcn_mfma_f32_16x16x32_bf16(Ah[1][kc].v, bh.v, acc1, 0, 0, 0);
        acc1 = __builtin_amdgcn_mfma_f32_16x16x32_bf16(Al[1][kc].v, bh.v, acc1, 0, 0, 0);
        acc1 = __builtin_amdgcn_mfma_f32_16x16x32_bf16(Ah[1][kc].v, blo.v, acc1, 0, 0, 0);
      }
    }
    int n = nt * 16 + m;
    float bv = (nt < 16) ? bxy[n] : 0.0f;
#pragma unroll
    for (int set = 0; set < 2; ++set) {
      f32x4 a = set ? acc1 : acc0;
#pragma unroll
      for (int i = 0; i < 4; ++i) {
        int row = r0 + set * 16 + q * 4 + i;
        unsigned short h = f2bf(a[i] + bv);
        if (nt < 8)       packed[(size_t)row * 384 + n] = h;
        else if (nt < 16) xrArr[(size_t)row * 128 + (n - 128)] = h;
        else              packed[(size_t)row * 384 + 128 + (n - 256)] = h;
      }
    }
  }
}

// ---------- CSR build ----------
__global__ __launch_bounds__(256) void k_hist(const int* __restrict__ edst,
                                              int* __restrict__ count, int E) {
  int e = blockIdx.x * 256 + threadIdx.x;
  if (e < E) atomicAdd(&count[edst[e]], 1);
}

// 1 block, 1024 thr; int4 loads, wave-shuffle scan (2 barriers)
__global__ __launch_bounds__(1024) void k_scan(const int* __restrict__ count,
                                               int* __restrict__ rowptr,
                                               int* __restrict__ cursor, int N, int E) {
  __shared__ int wtot[16];
  int t = threadIdx.x;
  int lane = t & 63, wv = t >> 6;
  int base4 = t * 8;            // int4 index
  int4 L[8];
  int s = 0;
#pragma unroll
  for (int i = 0; i < 8; ++i) {
    L[i] = ((const int4*)count)[base4 + i];
    s += L[i].x + L[i].y + L[i].z + L[i].w;
  }
  int incl = s;
#pragma unroll
  for (int off = 1; off < 64; off <<= 1) {
    int v = __shfl_up(incl, off);
    if (lane >= off) incl += v;
  }
  if (lane == 63) wtot[wv] = incl;
  __syncthreads();
  if (t < 16) {
    int v = wtot[t];
    int sc = v;
#pragma unroll
    for (int off = 1; off < 16; off <<= 1) {
      int u = __shfl_up(sc, off, 16);
      if (t >= off) sc += u;
    }
    wtot[t] = sc - v;           // exclusive wave offset
  }
  __syncthreads();
  int run = wtot[wv] + (incl - s);
#pragma unroll
  for (int i = 0; i < 8; ++i) {
    int4 c = L[i];
    int4 r;
    r.x = run; run += c.x;
    r.y = run; run += c.y;
    r.z = run; run += c.z;
    r.w = run; run += c.w;
    ((int4*)rowptr)[base4 + i] = r;
    ((int4*)cursor)[base4 + i] = r;
  }
  if (t == 1023) rowptr[N] = E;
}

__global__ __launch_bounds__(256) void k_scatter(const int* __restrict__ esrc,
                                                 const int* __restrict__ edst,
                                                 const float* __restrict__ pos,
                                                 int* __restrict__ cursor,
                                                 nf4* __restrict__ meta, int E) {
  int e = blockIdx.x * 256 + threadIdx.x;
  if (e >= E) return;
  int src = esrc[e], dst = edst[e];
  int p = atomicAdd(&cursor[dst], 1);
  float2 ps = *(const float2*)(pos + 2 * src);
  float2 pd = *(const float2*)(pos + 2 * dst);
  float dx = ps.x - pd.x, dy = ps.y - pd.y;
  float d2 = fmaxf(dx * dx + dy * dy, 1e-8f);
  nf4 v = {__int_as_float(src), -dy / d2, dx / d2, 0.0f};
  __builtin_nontemporal_store(v, &meta[p]);
}

// ---------- fused edge: logit + online softmax + aggregate; one wave per dst ----------
__device__ __forceinline__ void edge_step(nf4 mt, const unsigned* __restrict__ packedW,
                                          int lane, float2 xr, float2 Ad, float2 Bd,
                                          float a0, float a1,
                                          float& m, float& l, float2& s) {
  int si = __float_as_int(mt.x);
  const unsigned* pr = packedW + (size_t)si * 192;   // 384 bf16 = 192 words
  unsigned wxl = pr[lane];
  unsigned wA  = pr[64 + lane];
  unsigned wB  = pr[128 + lane];
  float2 xl = make_float2(__uint_as_float(wxl << 16), __uint_as_float(wxl & 0xFFFF0000u));
  float2 A  = make_float2(__uint_as_float(wA << 16),  __uint_as_float(wA & 0xFFFF0000u));
  float2 B  = make_float2(__uint_as_float(wB << 16),  __uint_as_float(wB & 0xFFFF0000u));
  float2 z = pk_add2(xl, xr);
  z = pk_fma2(make_float2(mt.y, mt.y), pk_sub2(A, Ad), z);
  z = pk_fma2(make_float2(mt.z, mt.z), pk_sub2(B, Bd), z);
  float2 zl = pk_max2(z, pk_muls2(z, 0.2f));          // leaky = max(z, 0.2z)
  float p = fmaf(a0, zl.x, a1 * zl.y);
#pragma unroll
  for (int mm = 8; mm >= 1; mm >>= 1) p += __shfl_xor(p, mm);
  if (p <= m) {                      // common: max unchanged (group-uniform branch)
    float ex = expf(p - m);
    l += ex;
    s = pk_fma2(make_float2(ex, ex), xl, s);
  } else {                           // rare: rescale state (first iter: m=-inf -> sc=0)
    float sc = expf(m - p);
    l = fmaf(l, sc, 1.0f);
    s = pk_fma2(make_float2(sc, sc), s, xl);
    m = p;
  }
}

__global__ __launch_bounds__(256) void k_edge(const int* __restrict__ rowptr,
                                              const nf4* __restrict__ meta,
                                              const unsigned short* __restrict__ packed,
                                              const unsigned short* __restrict__ xrArr,
                                              const float* __restrict__ att,
                                              float* __restrict__ aggr, int N) {
  int tid = threadIdx.x;
  int d = blockIdx.x * 4 + (tid >> 6);
  if (d >= N) return;
  int lane = tid & 63;
  int c0 = lane * 2;
  float2 av = *(const float2*)(att + c0);
  const unsigned* packedW = (const unsigned*)packed;
  float2 xr, Ad, Bd;
  ld2bf(xrArr + (size_t)d * 128 + c0, xr.x, xr.y);
  {
    const unsigned* pd = packedW + (size_t)d * 192;
    unsigned wA = pd[64 + lane], wB = pd[128 + lane];
    Ad = make_float2(__uint_as_float(wA << 16), __uint_as_float(wA & 0xFFFF0000u));
    Bd = make_float2(__uint_as_float(wB << 16), __uint_as_float(wB & 0xFFFF0000u));
  }
  int beg = rowptr[d], end = rowptr[d + 1];
  float m1 = -INFINITY, l1 = 0.f; float2 s1 = make_float2(0.f, 0.f);
  float m2 = -INFINITY, l2 = 0.f; float2 s2 = make_float2(0.f, 0.f);
  int j = beg;
  for (; j + 1 < end; j += 2) {
    nf4 mta = __builtin_nontemporal_load(&meta[j]);
    nf4 mtb = __builtin_nontemporal_load(&meta[j + 1]);
    edge_step(mta, packedW, lane, xr, Ad, Bd, av.x, av.y, m1, l1, s1);
    edge_step(mtb, packedW, lane, xr, Ad, Bd, av.x, av.y, m2, l2, s2);
  }
  if (j < end) {
    nf4 mta = __builtin_nontemporal_load(&meta[j]);
    edge_step(mta, packedW, lane, xr, Ad, Bd, av.x, av.y, m1, l1, s1);
  }
  float nm = fmaxf(m1, m2);
  float sc1 = (m1 == nm) ? 1.0f : expf(m1 - nm);
  float sc2 = (m2 == nm) ? 1.0f : expf(m2 - nm);
  float l = fmaf(l1, sc1, l2 * sc2);
  float o0 = fmaf(s1.x, sc1, s2.x * sc2);
  float o1 = fmaf(s1.y, sc1, s2.y * sc2);
  float inv = 1.0f / (l + 1e-16f);
  *(float2*)&aggr[(size_t)d * 128 + c0] = make_float2(o0 * inv, o1 * inv);
}

// ---------- fused MLP tail: t=aggr@Wpost+bpost2 -> LN -> u=gelu(t@W1+b1) -> out=u@W2+b2+resid ----------
__global__ __launch_bounds__(256) void k_mlp(const float* __restrict__ aggr,
                                             const unsigned short* __restrict__ WpT,
                                             const unsigned short* __restrict__ W1T,
                                             const unsigned short* __restrict__ W2T,
                                             const float* __restrict__ bpost2,
                                             const float* __restrict__ b1,
                                             const float* __restrict__ b2,
                                             const float* __restrict__ ln_g,
                                             const float* __restrict__ ln_b,
                                             const float* __restrict__ h_target,
                                             float* __restrict__ out) {
  __shared__ unsigned short Tb[64 * 136];
  __shared__ unsigned short Ub[64 * 136];
  int tid = threadIdx.x, wave = tid >> 6, lane = tid & 63;
  int m = lane & 15, q = lane >> 4;
  int r0 = blockIdx.x * 64 + wave * 16;
  int rb0 = wave * 16;
  BF8 Af[4];
  {
    const float* arow = aggr + (size_t)(r0 + m) * 128 + q * 8;
#pragma unroll
    for (int kc = 0; kc < 4; ++kc) {
      float4 x0 = *(const float4*)(arow + kc * 32);
      float4 x1 = *(const float4*)(arow + kc * 32 + 4);
      float xs[8] = {x0.x, x0.y, x0.z, x0.w, x1.x, x1.y, x1.z, x1.w};
#pragma unroll
      for (int jj = 0; jj < 8; ++jj) Af[kc].s[jj] = f2bf(xs[jj]);
    }
  }
  f32x4 acc[8];
#pragma unroll
  for (int t = 0; t < 8; ++t) {
    const unsigned short* wr = WpT + (size_t)(t * 16 + m) * 128 + q * 8;
    f32x4 a = {0.f, 0.f, 0.f, 0.f};
#pragma unroll
    for (int kc = 0; kc < 4; ++kc) {
      BF8 bh; bh.u = *(const uint4*)(wr + kc * 32);
      a = __builtin_amdgcn_mfma_f32_16x16x32_bf16(Af[kc].v, bh.v, a, 0, 0, 0);
    }
    acc[t] = a;
  }
  float sum[4] = {0, 0, 0, 0}, sq[4] = {0, 0, 0, 0};
#pragma unroll
  for (int t = 0; t < 8; ++t) {
    float bv = bpost2[t * 16 + m];
#pragma unroll
    for (int i = 0; i < 4; ++i) {
      float v = acc[t][i] + bv;
      acc[t][i] = v;
      sum[i] += v;
      sq[i] += v * v;
    }
  }
#pragma unroll
  for (int i = 0; i < 4; ++i) {
#pragma unroll
    for (int w = 1; w <= 8; w <<= 1) {
      sum[i] += __shfl_xor(sum[i], w);
      sq[i] += __shfl_xor(sq[i], w);
    }
  }
  float mu[4], rv[4];
#pragma unroll
  for (int i = 0; i < 4; ++i) {
    mu[i] = sum[i] * (1.0f / 128.0f);
    float var = sq[i] * (1.0f / 128.0f) - mu[i] * mu[i];
    rv[i] = rsqrtf(var + 1e-5f);
  }
#pragma unroll
  for (int t = 0; t < 8; ++t) {
    int n = t * 16 + m;
    float g = ln_g[n], b = ln_b[n];
#pragma unroll
    for (int i = 0; i < 4; ++i) {
      float v = (acc[t][i] - mu[i]) * rv[i] * g + b;
      Tb[(rb0 + q * 4 + i) * 136 + n] = f2bf(v);
    }
  }
  __syncthreads();
  BF8 Bf[4];
  {
    const unsigned short* tp = Tb + (rb0 + m) * 136 + q * 8;
#pragma unroll
    for (int kc = 0; kc < 4; ++kc) Bf[kc].u = *(const uint4*)(tp + kc * 32);
  }
#pragma unroll
  for (int t = 0; t < 8; ++t) {
    const unsigned short* wr = W1T + (size_t)(t * 16 + m) * 128 + q * 8;
    f32x4 a = {0.f, 0.f, 0.f, 0.f};
#pragma unroll
    for (int kc = 0; kc < 4; ++kc) {
      BF8 bh; bh.u = *(const uint4*)(wr + kc * 32);
      a = __builtin_amdgcn_mfma_f32_16x16x32_bf16(Bf[kc].v, bh.v, a, 0, 0, 0);
    }
    acc[t] = a;
  }
#pragma unroll
  for (int t = 0; t < 8; ++t) {
    int n = t * 16 + m;
    float bv = b1[n];
#pragma unroll
    for (int i = 0; i < 4; ++i) {
      float v = acc[t][i] + bv;
      v = 0.5f * v * (1.0f + erff(v * 0.70710678118654752f));
      Ub[(rb0 + q * 4 + i) * 136 + n] = f2bf(v);
    }
  }
  __syncthreads();
  BF8 Cf[4];
  {
    const unsigned short* up = Ub + (rb0 + m) * 136 + q * 8;
#pragma unroll
    for (int kc = 0; kc < 4; ++kc) Cf[kc].u = *(const uint4*)(up + kc * 32);
  }
#pragma unroll
  for (int t = 0; t < 8; ++t) {
    const unsigned short* wr = W2T + (size_t)(t * 16 + m) * 128 + q * 8;
    f32x4 a = {0.f, 0.f, 0.f, 0.f};
#pragma unroll
    for (int kc = 0; kc < 4; ++kc) {
      BF8 bh; bh.u = *(const uint4*)(wr + kc * 32);
      a = __builtin_amdgcn_mfma_f32_16x16x32_bf16(Cf[kc].v, bh.v, a, 0, 0, 0);
    }
    int n = t * 16 + m;
    float bv = b2[n];
#pragma unroll
    for (int i = 0; i < 4; ++i) {
      size_t off = (size_t)(r0 + q * 4 + i) * 128 + n;
      out[off] = a[i] + bv + h_target[off];
    }
  }
}

extern "C" void kernel_launch(void* const* d_in, const int* in_sizes, int n_in,
                              void* d_out, int out_size, void* d_ws, size_t ws_size,
                              hipStream_t stream) {
  const float* h_target = (const float*)d_in[0];
  const float* h_source = (const float*)d_in[1];
  const float* pos      = (const float*)d_in[2];
  const float* t_emb    = (const float*)d_in[3];
  const int*   eidx     = (const int*)d_in[4];
  const float* gn_gamma = (const float*)d_in[5];
  const float* gn_beta  = (const float*)d_in[6];
  const float* fc_W     = (const float*)d_in[7];
  const float* fc_b     = (const float*)d_in[8];
  const float* Wl       = (const float*)d_in[9];
  const float* bl       = (const float*)d_in[10];
  const float* Wr       = (const float*)d_in[11];
  const float* br       = (const float*)d_in[12];
  const float* We       = (const float*)d_in[13];
  const float* att      = (const float*)d_in[14];
  const float* gat_bias = (const float*)d_in[15];
  const float* Wpost    = (const float*)d_in[16];
  const float* bpost    = (const float*)d_in[17];
  const float* ln_g     = (const float*)d_in[18];
  const float* ln_b     = (const float*)d_in[19];
  const float* W1       = (const float*)d_in[20];
  const float* b1       = (const float*)d_in[21];
  const float* W2       = (const float*)d_in[22];
  const float* b2       = (const float*)d_in[23];

  const int N = in_sizes[0] / HID;     // 32768
  const int E = in_sizes[4] / 2;       // 524288
  const int* esrc = eidx;
  const int* edst = eidx + E;

  // ---- workspace (float offsets; MF = 1M floats = 4MB) ----
  float* ws = (float*)d_ws;
  const size_t MF = 1024 * 1024;
  float* style  = ws;                              // [0,8MF) fp32, dead after k_nodeP
  float* aggr   = ws;                              // [0,4MF) after k_edge
  unsigned short* packed = (unsigned short*)(ws + 8 * MF);   // [N][384] bf16
  unsigned short* xrArr  = (unsigned short*)(ws + 14 * MF);  // [N][128] bf16
  nf4*   meta   = (nf4*)(ws + 16 * MF);            // [E]
  int*   rowptr = (int*)(ws + 18 * MF);
  int*   count  = rowptr + 32832;
  int*   cursor = count + 32832;
  unsigned short* wgt = (unsigned short*)(ws + 18 * MF + 131072);
  unsigned short* fcTh = wgt;
  unsigned short* fcTl = wgt + 32768;
  unsigned short* WnTh = wgt + 65536;
  unsigned short* WnTl = wgt + 131072;
  unsigned short* WpT  = wgt + 163840;
  unsigned short* W1T  = wgt + 180224;
  unsigned short* W2T  = wgt + 196608;
  float* bxy    = (float*)(wgt + 212992);
  float* bpost2 = bxy + 256;
  const size_t needed = (size_t)(18 * MF + 131072 + 106496 + 512) * 4;
  if (ws_size < needed) return;  // visible failure (out stays poisoned)

  dim3 blk(256);

  // 1. prep
  prep3<<<578, blk, 0, stream>>>(fc_W, Wl, Wr, We, Wpost, W1, W2, bl, br, gat_bias, bpost,
                                 fcTh, fcTl, WnTh, WnTl, WpT, W1T, W2T, bxy, bpost2);
  // 2. style = t_emb @ fc_W + fc_b  [N x 256]  (split precision)
  gemm_mfma<<<N / 64, blk, 0, stream>>>(t_emb, fcTh, fcTl, fc_b, style, 256);
  // 3. fused GN+modulate + node GEMM -> packed [xl|A|B] bf16, xr bf16
  k_nodeP<<<N / 128, blk, 0, stream>>>(h_source, style, gn_gamma, gn_beta, WnTh, WnTl, bxy,
                                       packed, xrArr);
  // 4. CSR build
  (void)hipMemsetAsync(count, 0, (size_t)N * 4, stream);
  k_hist<<<(E + 255) / 256, blk, 0, stream>>>(edst, count, E);
  k_scan<<<1, 1024, 0, stream>>>(count, rowptr, cursor, N, E);
  k_scatter<<<(E + 255) / 256, blk, 0, stream>>>(esrc, edst, pos, cursor, meta, E);
  // 5. fused edge pass -> aggr (style region now dead)
  k_edge<<<(N + 3) / 4, blk, 0, stream>>>(rowptr, meta, packed, xrArr, att, aggr, N);
  // 6. fused MLP tail -> out
  k_mlp<<<N / 64, blk, 0, stream>>>(aggr, WpT, W1T, W2T, bpost2, b1, b2, ln_g, ln_b,
                                    h_target, (float*)d_out);
}

// Round 7
// 363.548 us; speedup vs baseline: 1.0840x; 1.0840x over previous
//
#include <hip/hip_runtime.h>
#include <hip/hip_bf16.h>
#include <math.h>

#define HID 128

typedef __bf16 bf16x8 __attribute__((ext_vector_type(8)));
typedef float f32x4 __attribute__((ext_vector_type(4)));
typedef float nf4 __attribute__((ext_vector_type(4)));
union BF8 { uint4 u; bf16x8 v; unsigned short s[8]; };

__device__ __forceinline__ unsigned short f2bf(float x) {
  unsigned u = __float_as_uint(x);
  unsigned r = u + 0x7FFFu + ((u >> 16) & 1u);   // RNE (finite inputs)
  return (unsigned short)(r >> 16);
}
__device__ __forceinline__ float bf2f(unsigned short h) {
  return __uint_as_float(((unsigned)h) << 16);
}
__device__ __forceinline__ void ld2bf(const unsigned short* p, float& x, float& y) {
  unsigned v = *(const unsigned*)p;
  x = __uint_as_float((v & 0xFFFFu) << 16);
  y = __uint_as_float(v & 0xFFFF0000u);
}
__device__ __forceinline__ float2 pk_add2(float2 a, float2 b) {
  return make_float2(a.x + b.x, a.y + b.y);
}
__device__ __forceinline__ float2 pk_sub2(float2 a, float2 b) {
  return make_float2(a.x - b.x, a.y - b.y);
}
__device__ __forceinline__ float2 pk_fma2(float2 a, float2 b, float2 c) {
  return make_float2(fmaf(a.x, b.x, c.x), fmaf(a.y, b.y, c.y));
}
__device__ __forceinline__ float2 pk_max2(float2 a, float2 b) {
  return make_float2(fmaxf(a.x, b.x), fmaxf(a.y, b.y));
}
__device__ __forceinline__ float2 pk_muls2(float2 a, float b) {
  return make_float2(a.x * b, a.y * b);
}

// ================= K1: prep (blocks 0..577) + hist (blocks 578..) =================
__global__ __launch_bounds__(256) void k1_prep_hist(
    const float* __restrict__ fc_W, const float* __restrict__ Wl,
    const float* __restrict__ Wr, const float* __restrict__ We,
    const float* __restrict__ Wpost, const float* __restrict__ W1,
    const float* __restrict__ W2, const float* __restrict__ bl,
    const float* __restrict__ br, const float* __restrict__ gat_bias,
    const float* __restrict__ bpost,
    unsigned short* __restrict__ fcTh, unsigned short* __restrict__ fcTl,
    unsigned short* __restrict__ WnTh, unsigned short* __restrict__ WnTl,
    unsigned short* __restrict__ WpT, unsigned short* __restrict__ W1T,
    unsigned short* __restrict__ W2T,
    float* __restrict__ bxy, float* __restrict__ bpost2,
    const int* __restrict__ edst, int* __restrict__ count, int E) {
  int bid = blockIdx.x;
  if (bid >= 578) {                        // ---- histogram part ----
    int e = (bid - 578) * 256 + threadIdx.x;
    if (e < E) atomicAdd(&count[edst[e]], 1);
    return;
  }
  int gid = bid * 256 + threadIdx.x;
  if (gid < 32768) {                       // fc_W [128x256] -> fcT hi/lo [256][128]
    int n = gid >> 7, k = gid & 127;
    float x = fc_W[k * 256 + n];
    unsigned short h = f2bf(x);
    fcTh[n * 128 + k] = h;
    fcTl[n * 128 + k] = f2bf(x - bf2f(h));
  } else if (gid < 98304) {                // WnT [512][128] cols=[Wl|Wr|WeA|WeB]
    int i = gid - 32768; int n = i >> 7, k = i & 127;
    float x;
    if (n < 128)      x = Wl[k * 128 + n];
    else if (n < 256) x = Wr[k * 128 + (n - 128)];
    else if (n < 384) x = We[k * 128 + (n - 256)];
    else              x = We[(128 + k) * 128 + (n - 384)];
    unsigned short h = f2bf(x);
    WnTh[n * 128 + k] = h;
    if (n >= 256) WnTl[(n - 256) * 128 + k] = f2bf(x - bf2f(h));
  } else if (gid < 147456) {               // Wpost/W1/W2 -> T [128][128]
    int i = gid - 98304; int which = i >> 14; int j = i & 16383;
    int n = j >> 7, k = j & 127;
    const float* W = (which == 0) ? Wpost : (which == 1) ? W1 : W2;
    unsigned short* T = (which == 0) ? WpT : (which == 1) ? W1T : W2T;
    T[n * 128 + k] = f2bf(W[k * 128 + n]);
  } else if (gid < 147712) {               // bxy = [bl|br]
    int j = gid - 147456;
    bxy[j] = (j < 128) ? bl[j] : br[j - 128];
  } else if (gid < 147840) {               // bpost2 = bpost + gat_bias @ Wpost
    int t = gid - 147712;
    float s = bpost[t];
    for (int k = 0; k < 128; ++k) s += gat_bias[k] * Wpost[k * 128 + t];
    bpost2[t] = s;
  }
}

// ================= K2: style GEMM (blocks 0..511) + scan (block 512) =================
// style = t_emb @ fc_W + fc_b [N x 256], split hi/lo precision.
__global__ __launch_bounds__(256) void k2_style_scan(
    const float* __restrict__ A, const unsigned short* __restrict__ WTh,
    const unsigned short* __restrict__ WTl, const float* __restrict__ bias,
    float* __restrict__ C,
    const int* __restrict__ count, int* __restrict__ rowptr,
    int* __restrict__ cursor, int N, int E) {
  if (blockIdx.x == 512) {                 // ---- scan part (2-pass, 256 thr) ----
    __shared__ int wtot[4];
    int t = threadIdx.x, lane = t & 63, wv = t >> 6;
    const int4* c4 = (const int4*)count;
    int base = t * 32;
    int s = 0;
    for (int i = 0; i < 32; ++i) {
      int4 c = c4[base + i];
      s += c.x + c.y + c.z + c.w;
    }
    int incl = s;
#pragma unroll
    for (int off = 1; off < 64; off <<= 1) {
      int v = __shfl_up(incl, off);
      if (lane >= off) incl += v;
    }
    if (lane == 63) wtot[wv] = incl;
    __syncthreads();
    if (t == 0) {
      int a0 = wtot[0], a1 = wtot[1], a2 = wtot[2];
      wtot[0] = 0; wtot[1] = a0; wtot[2] = a0 + a1; wtot[3] = a0 + a1 + a2;
    }
    __syncthreads();
    int run = wtot[wv] + incl - s;
    for (int i = 0; i < 32; ++i) {
      int4 c = c4[base + i];
      int4 r;
      r.x = run; run += c.x;
      r.y = run; run += c.y;
      r.z = run; run += c.z;
      r.w = run; run += c.w;
      ((int4*)rowptr)[base + i] = r;
      ((int4*)cursor)[base + i] = r;
    }
    if (t == 255) rowptr[N] = E;
    return;
  }
  // ---- style GEMM part ----
  int tid = threadIdx.x;
  int wave = tid >> 6, lane = tid & 63;
  int m = lane & 15, q = lane >> 4;
  int r0 = blockIdx.x * 64 + wave * 16;
  const float* arow = A + (size_t)(r0 + m) * 128 + q * 8;
  BF8 Ah[4], Al[4];
#pragma unroll
  for (int kc = 0; kc < 4; ++kc) {
    float4 x0 = *(const float4*)(arow + kc * 32);
    float4 x1 = *(const float4*)(arow + kc * 32 + 4);
    float xs[8] = {x0.x, x0.y, x0.z, x0.w, x1.x, x1.y, x1.z, x1.w};
#pragma unroll
    for (int j = 0; j < 8; ++j) {
      unsigned short h = f2bf(xs[j]);
      Ah[kc].s[j] = h;
      Al[kc].s[j] = f2bf(xs[j] - bf2f(h));
    }
  }
  for (int nt = 0; nt < 16; ++nt) {
    const unsigned short* wr  = WTh + (size_t)(nt * 16 + m) * 128 + q * 8;
    const unsigned short* wrl = WTl + (size_t)(nt * 16 + m) * 128 + q * 8;
    f32x4 acc = {0.f, 0.f, 0.f, 0.f};
#pragma unroll
    for (int kc = 0; kc < 4; ++kc) {
      BF8 bh, blo;
      bh.u  = *(const uint4*)(wr + kc * 32);
      blo.u = *(const uint4*)(wrl + kc * 32);
      acc = __builtin_amdgcn_mfma_f32_16x16x32_bf16(Ah[kc].v, bh.v, acc, 0, 0, 0);
      acc = __builtin_amdgcn_mfma_f32_16x16x32_bf16(Al[kc].v, bh.v, acc, 0, 0, 0);
      acc = __builtin_amdgcn_mfma_f32_16x16x32_bf16(Ah[kc].v, blo.v, acc, 0, 0, 0);
    }
    int n = nt * 16 + m;
    float bv = bias[n];
#pragma unroll
    for (int i = 0; i < 4; ++i) {
      int row = r0 + q * 4 + i;
      C[(size_t)row * 256 + n] = acc[i] + bv;
    }
  }
}

// ================= K3: nodeP (blocks 0..255) + scatter (blocks 256..) =================
__global__ __launch_bounds__(256) void k3_node_scatter(
    const float* __restrict__ h_source, const float* __restrict__ style,
    const float* __restrict__ gn_gamma, const float* __restrict__ gn_beta,
    const unsigned short* __restrict__ WnTh, const unsigned short* __restrict__ WnTl,
    const float* __restrict__ bxy,
    unsigned short* __restrict__ packed, unsigned short* __restrict__ xrArr,
    const int* __restrict__ esrc, const int* __restrict__ edst,
    const float* __restrict__ pos, int* __restrict__ cursor,
    nf4* __restrict__ meta, int E) {
  int bid = blockIdx.x;
  if (bid >= 256) {                        // ---- scatter part ----
    int e = (bid - 256) * 256 + threadIdx.x;
    if (e >= E) return;
    int src = esrc[e], dst = edst[e];
    int p = atomicAdd(&cursor[dst], 1);
    float2 ps = *(const float2*)(pos + 2 * src);
    float2 pd = *(const float2*)(pos + 2 * dst);
    float dx = ps.x - pd.x, dy = ps.y - pd.y;
    float d2 = fmaxf(dx * dx + dy * dy, 1e-8f);
    nf4 v = {__int_as_float(src), -dy / d2, dx / d2, 0.0f};
    meta[p] = v;
    return;
  }
  // ---- nodeP part: GN+modulate inline A-build + dual-output node GEMM ----
  int tid = threadIdx.x, wave = tid >> 6, lane = tid & 63;
  int m = lane & 15, q = lane >> 4;
  int r0 = bid * 128 + wave * 32;
  BF8 Ah[2][4], Al[2][4];
#pragma unroll
  for (int set = 0; set < 2; ++set) {
    int r = r0 + set * 16 + m;
    const float* hrow = h_source + (size_t)r * 128;
    const float* srow = style + (size_t)r * 256;
#pragma unroll
    for (int kc = 0; kc < 4; ++kc) {
      int ch = q * 8 + kc * 32;
      float4 x0 = *(const float4*)(hrow + ch);
      float4 x1 = *(const float4*)(hrow + ch + 4);
      float xs[8] = {x0.x, x0.y, x0.z, x0.w, x1.x, x1.y, x1.z, x1.w};
      float s8 = 0.f, q8 = 0.f;
#pragma unroll
      for (int j = 0; j < 8; ++j) { s8 += xs[j]; q8 += xs[j] * xs[j]; }
      float s16 = s8 + __shfl_xor(s8, 16);
      float q16 = q8 + __shfl_xor(q8, 16);
      float mu = s16 * (1.0f / 16.0f);
      float var = q16 * (1.0f / 16.0f) - mu * mu;
      float rv = rsqrtf(var + 1e-5f);
      float4 g0 = *(const float4*)(gn_gamma + ch);
      float4 g1 = *(const float4*)(gn_gamma + ch + 4);
      float4 be0 = *(const float4*)(gn_beta + ch);
      float4 be1 = *(const float4*)(gn_beta + ch + 4);
      float4 sg0 = *(const float4*)(srow + ch);
      float4 sg1 = *(const float4*)(srow + ch + 4);
      float4 sb0 = *(const float4*)(srow + 128 + ch);
      float4 sb1 = *(const float4*)(srow + 128 + ch + 4);
      float gg[8] = {g0.x, g0.y, g0.z, g0.w, g1.x, g1.y, g1.z, g1.w};
      float bb[8] = {be0.x, be0.y, be0.z, be0.w, be1.x, be1.y, be1.z, be1.w};
      float sg[8] = {sg0.x, sg0.y, sg0.z, sg0.w, sg1.x, sg1.y, sg1.z, sg1.w};
      float sb[8] = {sb0.x, sb0.y, sb0.z, sb0.w, sb1.x, sb1.y, sb1.z, sb1.w};
#pragma unroll
      for (int j = 0; j < 8; ++j) {
        float v = ((xs[j] - mu) * rv * gg[j] + bb[j]) * (1.0f + sg[j]) + sb[j];
        unsigned short h = f2bf(v);
        Ah[set][kc].s[j] = h;
        Al[set][kc].s[j] = f2bf(v - bf2f(h));
      }
    }
  }
  for (int nt = 0; nt < 32; ++nt) {
    f32x4 acc0 = {0.f, 0.f, 0.f, 0.f};
    f32x4 acc1 = {0.f, 0.f, 0.f, 0.f};
    const unsigned short* wr = WnTh + (size_t)(nt * 16 + m) * 128 + q * 8;
    if (nt < 16) {
#pragma unroll
      for (int kc = 0; kc < 4; ++kc) {
        BF8 bh; bh.u = *(const uint4*)(wr + kc * 32);
        acc0 = __builtin_amdgcn_mfma_f32_16x16x32_bf16(Ah[0][kc].v, bh.v, acc0, 0, 0, 0);
        acc1 = __builtin_amdgcn_mfma_f32_16x16x32_bf16(Ah[1][kc].v, bh.v, acc1, 0, 0, 0);
      }
    } else {
      const unsigned short* wl = WnTl + (size_t)((nt - 16) * 16 + m) * 128 + q * 8;
#pragma unroll
      for (int kc = 0; kc < 4; ++kc) {
        BF8 bh, blo;
        bh.u  = *(const uint4*)(wr + kc * 32);
        blo.u = *(const uint4*)(wl + kc * 32);
        acc0 = __builtin_amdgcn_mfma_f32_16x16x32_bf16(Ah[0][kc].v, bh.v, acc0, 0, 0, 0);
        acc0 = __builtin_amdgcn_mfma_f32_16x16x32_bf16(Al[0][kc].v, bh.v, acc0, 0, 0, 0);
        acc0 = __builtin_amdgcn_mfma_f32_16x16x32_bf16(Ah[0][kc].v, blo.v, acc0, 0, 0, 0);
        acc1 = __builtin_amdgcn_mfma_f32_16x16x32_bf16(Ah[1][kc].v, bh.v, acc1, 0, 0, 0);
        acc1 = __builtin_amdgcn_mfma_f32_16x16x32_bf16(Al[1][kc].v, bh.v, acc1, 0, 0, 0);
        acc1 = __builtin_amdgcn_mfma_f32_16x16x32_bf16(Ah[1][kc].v, blo.v, acc1, 0, 0, 0);
      }
    }
    int n = nt * 16 + m;
    float bv = (nt < 16) ? bxy[n] : 0.0f;
#pragma unroll
    for (int set = 0; set < 2; ++set) {
      f32x4 a = set ? acc1 : acc0;
#pragma unroll
      for (int i = 0; i < 4; ++i) {
        int row = r0 + set * 16 + q * 4 + i;
        unsigned short h = f2bf(a[i] + bv);
        if (nt < 8)       packed[(size_t)row * 384 + n] = h;
        else if (nt < 16) xrArr[(size_t)row * 128 + (n - 128)] = h;
        else              packed[(size_t)row * 384 + 128 + (n - 256)] = h;
      }
    }
  }
}

// ================= K4: fused edge pass =================
__device__ __forceinline__ void edge_step(nf4 mt, const unsigned* __restrict__ packedW,
                                          int lane, float2 xr, float2 Ad, float2 Bd,
                                          float a0, float a1,
                                          float& m, float& l, float2& s) {
  int si = __float_as_int(mt.x);
  const unsigned* pr = packedW + (size_t)si * 192;   // 384 bf16 = 192 words
  unsigned wxl = pr[lane];
  unsigned wA  = pr[64 + lane];
  unsigned wB  = pr[128 + lane];
  float2 xl = make_float2(__uint_as_float(wxl << 16), __uint_as_float(wxl & 0xFFFF0000u));
  float2 A  = make_float2(__uint_as_float(wA << 16),  __uint_as_float(wA & 0xFFFF0000u));
  float2 B  = make_float2(__uint_as_float(wB << 16),  __uint_as_float(wB & 0xFFFF0000u));
  float2 z = pk_add2(xl, xr);
  z = pk_fma2(make_float2(mt.y, mt.y), pk_sub2(A, Ad), z);
  z = pk_fma2(make_float2(mt.z, mt.z), pk_sub2(B, Bd), z);
  float2 zl = pk_max2(z, pk_muls2(z, 0.2f));          // leaky = max(z, 0.2z)
  float p = fmaf(a0, zl.x, a1 * zl.y);
#pragma unroll
  for (int mm = 8; mm >= 1; mm >>= 1) p += __shfl_xor(p, mm);
  if (p <= m) {                      // common: max unchanged (group-uniform branch)
    float ex = expf(p - m);
    l += ex;
    s = pk_fma2(make_float2(ex, ex), xl, s);
  } else {                           // rare: rescale state (first iter: m=-inf -> sc=0)
    float sc = expf(m - p);
    l = fmaf(l, sc, 1.0f);
    s = pk_fma2(make_float2(sc, sc), s, xl);
    m = p;
  }
}

__global__ __launch_bounds__(256) void k_edge(const int* __restrict__ rowptr,
                                              const nf4* __restrict__ meta,
                                              const unsigned short* __restrict__ packed,
                                              const unsigned short* __restrict__ xrArr,
                                              const float* __restrict__ att,
                                              float* __restrict__ aggr, int N) {
  int tid = threadIdx.x;
  int d = blockIdx.x * 4 + (tid >> 6);
  if (d >= N) return;
  int lane = tid & 63;
  int c0 = lane * 2;
  float2 av = *(const float2*)(att + c0);
  const unsigned* packedW = (const unsigned*)packed;
  float2 xr, Ad, Bd;
  ld2bf(xrArr + (size_t)d * 128 + c0, xr.x, xr.y);
  {
    const unsigned* pd = packedW + (size_t)d * 192;
    unsigned wA = pd[64 + lane], wB = pd[128 + lane];
    Ad = make_float2(__uint_as_float(wA << 16), __uint_as_float(wA & 0xFFFF0000u));
    Bd = make_float2(__uint_as_float(wB << 16), __uint_as_float(wB & 0xFFFF0000u));
  }
  int beg = rowptr[d], end = rowptr[d + 1];
  float m1 = -INFINITY, l1 = 0.f; float2 s1 = make_float2(0.f, 0.f);
  float m2 = -INFINITY, l2 = 0.f; float2 s2 = make_float2(0.f, 0.f);
  int j = beg;
  if (j + 1 < end) {
    nf4 mt0 = meta[j], mt1 = meta[j + 1];      // software pipeline: meta 2 ahead
    for (; j + 3 < end; j += 2) {
      nf4 nx0 = meta[j + 2], nx1 = meta[j + 3];
      edge_step(mt0, packedW, lane, xr, Ad, Bd, av.x, av.y, m1, l1, s1);
      edge_step(mt1, packedW, lane, xr, Ad, Bd, av.x, av.y, m2, l2, s2);
      mt0 = nx0; mt1 = nx1;
    }
    edge_step(mt0, packedW, lane, xr, Ad, Bd, av.x, av.y, m1, l1, s1);
    edge_step(mt1, packedW, lane, xr, Ad, Bd, av.x, av.y, m2, l2, s2);
    j += 2;
  }
  if (j < end) {
    nf4 mt = meta[j];
    edge_step(mt, packedW, lane, xr, Ad, Bd, av.x, av.y, m1, l1, s1);
  }
  float nm = fmaxf(m1, m2);
  float sc1 = (m1 == nm) ? 1.0f : expf(m1 - nm);
  float sc2 = (m2 == nm) ? 1.0f : expf(m2 - nm);
  float l = fmaf(l1, sc1, l2 * sc2);
  float o0 = fmaf(s1.x, sc1, s2.x * sc2);
  float o1 = fmaf(s1.y, sc1, s2.y * sc2);
  float inv = 1.0f / (l + 1e-16f);
  *(float2*)&aggr[(size_t)d * 128 + c0] = make_float2(o0 * inv, o1 * inv);
}

// ================= K5: fused MLP tail =================
__global__ __launch_bounds__(256) void k_mlp(const float* __restrict__ aggr,
                                             const unsigned short* __restrict__ WpT,
                                             const unsigned short* __restrict__ W1T,
                                             const unsigned short* __restrict__ W2T,
                                             const float* __restrict__ bpost2,
                                             const float* __restrict__ b1,
                                             const float* __restrict__ b2,
                                             const float* __restrict__ ln_g,
                                             const float* __restrict__ ln_b,
                                             const float* __restrict__ h_target,
                                             float* __restrict__ out) {
  __shared__ unsigned short Tb[64 * 136];
  __shared__ unsigned short Ub[64 * 136];
  int tid = threadIdx.x, wave = tid >> 6, lane = tid & 63;
  int m = lane & 15, q = lane >> 4;
  int r0 = blockIdx.x * 64 + wave * 16;
  int rb0 = wave * 16;
  BF8 Af[4];
  {
    const float* arow = aggr + (size_t)(r0 + m) * 128 + q * 8;
#pragma unroll
    for (int kc = 0; kc < 4; ++kc) {
      float4 x0 = *(const float4*)(arow + kc * 32);
      float4 x1 = *(const float4*)(arow + kc * 32 + 4);
      float xs[8] = {x0.x, x0.y, x0.z, x0.w, x1.x, x1.y, x1.z, x1.w};
#pragma unroll
      for (int jj = 0; jj < 8; ++jj) Af[kc].s[jj] = f2bf(xs[jj]);
    }
  }
  f32x4 acc[8];
#pragma unroll
  for (int t = 0; t < 8; ++t) {
    const unsigned short* wr = WpT + (size_t)(t * 16 + m) * 128 + q * 8;
    f32x4 a = {0.f, 0.f, 0.f, 0.f};
#pragma unroll
    for (int kc = 0; kc < 4; ++kc) {
      BF8 bh; bh.u = *(const uint4*)(wr + kc * 32);
      a = __builtin_amdgcn_mfma_f32_16x16x32_bf16(Af[kc].v, bh.v, a, 0, 0, 0);
    }
    acc[t] = a;
  }
  float sum[4] = {0, 0, 0, 0}, sq[4] = {0, 0, 0, 0};
#pragma unroll
  for (int t = 0; t < 8; ++t) {
    float bv = bpost2[t * 16 + m];
#pragma unroll
    for (int i = 0; i < 4; ++i) {
      float v = acc[t][i] + bv;
      acc[t][i] = v;
      sum[i] += v;
      sq[i] += v * v;
    }
  }
#pragma unroll
  for (int i = 0; i < 4; ++i) {
#pragma unroll
    for (int w = 1; w <= 8; w <<= 1) {
      sum[i] += __shfl_xor(sum[i], w);
      sq[i] += __shfl_xor(sq[i], w);
    }
  }
  float mu[4], rv[4];
#pragma unroll
  for (int i = 0; i < 4; ++i) {
    mu[i] = sum[i] * (1.0f / 128.0f);
    float var = sq[i] * (1.0f / 128.0f) - mu[i] * mu[i];
    rv[i] = rsqrtf(var + 1e-5f);
  }
#pragma unroll
  for (int t = 0; t < 8; ++t) {
    int n = t * 16 + m;
    float g = ln_g[n], b = ln_b[n];
#pragma unroll
    for (int i = 0; i < 4; ++i) {
      float v = (acc[t][i] - mu[i]) * rv[i] * g + b;
      Tb[(rb0 + q * 4 + i) * 136 + n] = f2bf(v);
    }
  }
  __syncthreads();
  BF8 Bf[4];
  {
    const unsigned short* tp = Tb + (rb0 + m) * 136 + q * 8;
#pragma unroll
    for (int kc = 0; kc < 4; ++kc) Bf[kc].u = *(const uint4*)(tp + kc * 32);
  }
#pragma unroll
  for (int t = 0; t < 8; ++t) {
    const unsigned short* wr = W1T + (size_t)(t * 16 + m) * 128 + q * 8;
    f32x4 a = {0.f, 0.f, 0.f, 0.f};
#pragma unroll
    for (int kc = 0; kc < 4; ++kc) {
      BF8 bh; bh.u = *(const uint4*)(wr + kc * 32);
      a = __builtin_amdgcn_mfma_f32_16x16x32_bf16(Bf[kc].v, bh.v, a, 0, 0, 0);
    }
    acc[t] = a;
  }
#pragma unroll
  for (int t = 0; t < 8; ++t) {
    int n = t * 16 + m;
    float bv = b1[n];
#pragma unroll
    for (int i = 0; i < 4; ++i) {
      float v = acc[t][i] + bv;
      v = 0.5f * v * (1.0f + erff(v * 0.70710678118654752f));
      Ub[(rb0 + q * 4 + i) * 136 + n] = f2bf(v);
    }
  }
  __syncthreads();
  BF8 Cf[4];
  {
    const unsigned short* up = Ub + (rb0 + m) * 136 + q * 8;
#pragma unroll
    for (int kc = 0; kc < 4; ++kc) Cf[kc].u = *(const uint4*)(up + kc * 32);
  }
#pragma unroll
  for (int t = 0; t < 8; ++t) {
    const unsigned short* wr = W2T + (size_t)(t * 16 + m) * 128 + q * 8;
    f32x4 a = {0.f, 0.f, 0.f, 0.f};
#pragma unroll
    for (int kc = 0; kc < 4; ++kc) {
      BF8 bh; bh.u = *(const uint4*)(wr + kc * 32);
      a = __builtin_amdgcn_mfma_f32_16x16x32_bf16(Cf[kc].v, bh.v, a, 0, 0, 0);
    }
    int n = t * 16 + m;
    float bv = b2[n];
#pragma unroll
    for (int i = 0; i < 4; ++i) {
      size_t off = (size_t)(r0 + q * 4 + i) * 128 + n;
      out[off] = a[i] + bv + h_target[off];
    }
  }
}

extern "C" void kernel_launch(void* const* d_in, const int* in_sizes, int n_in,
                              void* d_out, int out_size, void* d_ws, size_t ws_size,
                              hipStream_t stream) {
  const float* h_target = (const float*)d_in[0];
  const float* h_source = (const float*)d_in[1];
  const float* pos      = (const float*)d_in[2];
  const float* t_emb    = (const float*)d_in[3];
  const int*   eidx     = (const int*)d_in[4];
  const float* gn_gamma = (const float*)d_in[5];
  const float* gn_beta  = (const float*)d_in[6];
  const float* fc_W     = (const float*)d_in[7];
  const float* fc_b     = (const float*)d_in[8];
  const float* Wl       = (const float*)d_in[9];
  const float* bl       = (const float*)d_in[10];
  const float* Wr       = (const float*)d_in[11];
  const float* br       = (const float*)d_in[12];
  const float* We       = (const float*)d_in[13];
  const float* att      = (const float*)d_in[14];
  const float* gat_bias = (const float*)d_in[15];
  const float* Wpost    = (const float*)d_in[16];
  const float* bpost    = (const float*)d_in[17];
  const float* ln_g     = (const float*)d_in[18];
  const float* ln_b     = (const float*)d_in[19];
  const float* W1       = (const float*)d_in[20];
  const float* b1       = (const float*)d_in[21];
  const float* W2       = (const float*)d_in[22];
  const float* b2       = (const float*)d_in[23];

  const int N = in_sizes[0] / HID;     // 32768
  const int E = in_sizes[4] / 2;       // 524288
  const int* esrc = eidx;
  const int* edst = eidx + E;

  // ---- workspace (float offsets; MF = 1M floats = 4MB) ----
  float* ws = (float*)d_ws;
  const size_t MF = 1024 * 1024;
  float* style  = ws;                              // [0,8MF) fp32, dead after K3
  float* aggr   = ws;                              // [0,4MF) after k_edge
  unsigned short* packed = (unsigned short*)(ws + 8 * MF);   // [N][384] bf16
  unsigned short* xrArr  = (unsigned short*)(ws + 14 * MF);  // [N][128] bf16
  nf4*   meta   = (nf4*)(ws + 16 * MF);            // [E]
  int*   rowptr = (int*)(ws + 18 * MF);
  int*   count  = rowptr + 32832;
  int*   cursor = count + 32832;
  unsigned short* wgt = (unsigned short*)(ws + 18 * MF + 131072);
  unsigned short* fcTh = wgt;
  unsigned short* fcTl = wgt + 32768;
  unsigned short* WnTh = wgt + 65536;
  unsigned short* WnTl = wgt + 131072;
  unsigned short* WpT  = wgt + 163840;
  unsigned short* W1T  = wgt + 180224;
  unsigned short* W2T  = wgt + 196608;
  float* bxy    = (float*)(wgt + 212992);
  float* bpost2 = bxy + 256;
  const size_t needed = (size_t)(18 * MF + 131072 + 106496 + 512) * 4;
  if (ws_size < needed) return;  // visible failure (out stays poisoned)

  dim3 blk(256);
  const int histB = (E + 255) / 256;   // 2048

  (void)hipMemsetAsync(count, 0, (size_t)N * 4, stream);
  // K1: prep (578) + hist (2048)
  k1_prep_hist<<<578 + histB, blk, 0, stream>>>(
      fc_W, Wl, Wr, We, Wpost, W1, W2, bl, br, gat_bias, bpost,
      fcTh, fcTl, WnTh, WnTl, WpT, W1T, W2T, bxy, bpost2, edst, count, E);
  // K2: style GEMM (512) + scan (1)
  k2_style_scan<<<513, blk, 0, stream>>>(t_emb, fcTh, fcTl, fc_b, style,
                                         count, rowptr, cursor, N, E);
  // K3: nodeP (256) + scatter (2048)
  k3_node_scatter<<<256 + histB, blk, 0, stream>>>(
      h_source, style, gn_gamma, gn_beta, WnTh, WnTl, bxy, packed, xrArr,
      esrc, edst, pos, cursor, meta, E);
  // K4: fused edge pass -> aggr (style region now dead)
  k_edge<<<(N + 3) / 4, blk, 0, stream>>>(rowptr, meta, packed, xrArr, att, aggr, N);
  // K5: fused MLP tail -> out
  k_mlp<<<N / 64, blk, 0, stream>>>(aggr, WpT, W1T, W2T, bpost2, b1, b2, ln_g, ln_b,
                                    h_target, (float*)d_out);
}